// Round 3
// baseline (400.055 us; speedup 1.0000x reference)
//
#include <hip/hip_runtime.h>
#include <math.h>

#define T_    2048
#define B_    2
#define E_    1024
#define H_    16
#define HD_   64
#define KD_   1024
#define N3_   3072
#define M_    4096
#define NEGI  -1e24f

typedef __attribute__((ext_vector_type(8))) short          bf16x8;
typedef __attribute__((ext_vector_type(4))) float          f32x4;
typedef __attribute__((ext_vector_type(8))) unsigned short u16x8;

__device__ __forceinline__ unsigned short f2bf(float x) {   // RNE fp32->bf16
    unsigned int u = __float_as_uint(x);
    return (unsigned short)((u + 0x7fffu + ((u >> 16) & 1u)) >> 16);
}

// ---------------------------------------------------------------------------
__global__ __launch_bounds__(256) void cvt_bf16(const float* __restrict__ s,
                                                unsigned short* __restrict__ d, int n4) {
    int i = blockIdx.x * 256 + threadIdx.x;
    if (i >= n4) return;
    float4 v = ((const float4*)s)[i];
    ushort4 o;
    o.x = f2bf(v.x); o.y = f2bf(v.y); o.z = f2bf(v.z); o.w = f2bf(v.w);
    ((ushort4*)d)[i] = o;
}

__global__ __launch_bounds__(256) void build_msk(const int* __restrict__ m,
                                                 float* __restrict__ o) {
    int i = blockIdx.x * 256 + threadIdx.x;          // i = t*B + b
    if (i >= T_ * B_) return;
    o[(i & 1) * T_ + (i >> 1)] = m[i] ? NEGI : 0.f;  // msk[b][t]
}

// ---------------------------------------------------------------------------
// bf16 MFMA GEMM: C[m][f] = sum_k A[m][k]*W[f][k] + bias[f]
// A [M][1024], W [N][1024] bf16 row-major. 128x128 tile, BK=64, 4 waves,
// each wave 64x64 = 4x4 frags of mfma_f32_16x16x32_bf16. LDS [row][64] bf16
// with 16B-block XOR swizzle (block ^= row&7) on BOTH write and read ->
// conflict-free ds_read_b128. Reg-staged (no global_load_lds builtin risk).
// EPI 0: scatter q (x0.125) / k / v as bf16 [b,h][t][d].  EPI 1: fp32 out.
// ---------------------------------------------------------------------------
template <int EPI>
__global__ __launch_bounds__(256) void gemm_mfma(
    const unsigned short* __restrict__ A, const unsigned short* __restrict__ W,
    const float* __restrict__ bias,
    unsigned short* __restrict__ q_o, unsigned short* __restrict__ k_o,
    unsigned short* __restrict__ v_o, float* __restrict__ f_o)
{
    __shared__ __align__(16) unsigned short Ab[128 * 64];
    __shared__ __align__(16) unsigned short Bb[128 * 64];
    const int tid = threadIdx.x;
    const int l = tid & 63, w = tid >> 6;
    const int lr = l & 15, g = l >> 4;
    const int m0 = blockIdx.y * 128, n0 = blockIdx.x * 128;
    const int wr = (w >> 1) * 64, wc = (w & 1) * 64;

    f32x4 acc[4][4];
    #pragma unroll
    for (int i = 0; i < 4; ++i)
        #pragma unroll
        for (int j = 0; j < 4; ++j) acc[i][j] = f32x4{0.f, 0.f, 0.f, 0.f};

    for (int k0 = 0; k0 < KD_; k0 += 64) {
        u16x8 ra[4], rb[4];
        #pragma unroll
        for (int i = 0; i < 4; ++i) {
            const int f   = (i * 4 + w) * 64 + l;      // 0..1023 -> tile slot
            const int row = f >> 3;
            const int sb  = (f & 7) ^ (row & 7);       // pre-swizzled src block
            ra[i] = *(const u16x8*)&A[(size_t)(m0 + row) * KD_ + k0 + sb * 8];
            rb[i] = *(const u16x8*)&W[(size_t)(n0 + row) * KD_ + k0 + sb * 8];
        }
        __syncthreads();                               // prior frag reads done
        #pragma unroll
        for (int i = 0; i < 4; ++i) {
            const int f = (i * 4 + w) * 64 + l;
            *(u16x8*)&Ab[f * 8] = ra[i];
            *(u16x8*)&Bb[f * 8] = rb[i];
        }
        __syncthreads();
        #pragma unroll
        for (int ks = 0; ks < 2; ++ks) {
            bf16x8 af[4], bf[4];
            #pragma unroll
            for (int mi = 0; mi < 4; ++mi) {
                const int row = wr + mi * 16 + lr;
                af[mi] = *(const bf16x8*)&Ab[row * 64 + (((ks * 4 + g) ^ (row & 7)) * 8)];
            }
            #pragma unroll
            for (int ni = 0; ni < 4; ++ni) {
                const int row = wc + ni * 16 + lr;
                bf[ni] = *(const bf16x8*)&Bb[row * 64 + (((ks * 4 + g) ^ (row & 7)) * 8)];
            }
            #pragma unroll
            for (int mi = 0; mi < 4; ++mi)
                #pragma unroll
                for (int ni = 0; ni < 4; ++ni)
                    acc[mi][ni] = __builtin_amdgcn_mfma_f32_16x16x32_bf16(
                        af[mi], bf[ni], acc[mi][ni], 0, 0, 0);
        }
    }

    // C/D layout: col = lane&15, row = (lane>>4)*4 + reg   [m89-verified]
    if (EPI == 0) {
        const int sec = n0 >> 10;                      // 0=q 1=k 2=v
        unsigned short* dst = (sec == 0) ? q_o : (sec == 1) ? k_o : v_o;
        const float sc = (sec == 0) ? 0.125f : 1.f;    // hd^-0.5
        #pragma unroll
        for (int ni = 0; ni < 4; ++ni) {
            const int fcol = n0 + wc + ni * 16 + lr;
            const int h = (fcol >> 6) & 15, d = fcol & 63;
            const float bv = bias[fcol];
            #pragma unroll
            for (int mi = 0; mi < 4; ++mi)
                #pragma unroll
                for (int p = 0; p < 4; ++p) {
                    const int m = m0 + wr + mi * 16 + g * 4 + p;
                    const int t = m >> 1, b = m & 1;   // row m = t*B + b
                    dst[((size_t)(b * H_ + h) * T_ + t) * HD_ + d] =
                        f2bf((acc[mi][ni][p] + bv) * sc);
                }
        }
    } else {
        #pragma unroll
        for (int ni = 0; ni < 4; ++ni) {
            const int fcol = n0 + wc + ni * 16 + lr;
            const float bv = bias[fcol];
            #pragma unroll
            for (int mi = 0; mi < 4; ++mi)
                #pragma unroll
                for (int p = 0; p < 4; ++p) {
                    const int m = m0 + wr + mi * 16 + g * 4 + p;
                    f_o[(size_t)m * E_ + fcol] = acc[mi][ni][p] + bv;
                }
        }
    }
}

// ---------------------------------------------------------------------------
// V [bh][t][d] -> Vt [bh][d][t]  (64x64 tiles through LDS)
// ---------------------------------------------------------------------------
__global__ __launch_bounds__(256) void transpose64(const unsigned short* __restrict__ v,
                                                   unsigned short* __restrict__ vt)
{
    __shared__ __align__(16) unsigned short tile[64][72];
    const int bh = blockIdx.y, t0 = blockIdx.x * 64;
    const int tid = threadIdx.x;
    const int r = tid >> 2, c0 = (tid & 3) * 16;
    const unsigned short* src = v + ((size_t)bh * T_ + t0 + r) * HD_ + c0;
    *(u16x8*)&tile[r][c0]     = *(const u16x8*)&src[0];
    *(u16x8*)&tile[r][c0 + 8] = *(const u16x8*)&src[8];
    __syncthreads();
    u16x8 a, b;
    #pragma unroll
    for (int j = 0; j < 8; ++j) a[j] = tile[c0 + j][r];       // r is d here
    #pragma unroll
    for (int j = 0; j < 8; ++j) b[j] = tile[c0 + 8 + j][r];
    unsigned short* dq = vt + ((size_t)bh * HD_ + r) * T_ + t0 + c0;
    *(u16x8*)&dq[0] = a;
    *(u16x8*)&dq[8] = b;
}

// ---------------------------------------------------------------------------
// Flash attention, bf16 MFMA, LDS-free except wave-private P bounce.
// Block = 4 waves x 16 q-rows (64 q). No __syncthreads anywhere.
// S^T = K.Q^T per 16x16x32 MFMA: lane holds S[s = sf*16+4g+p][q = lane&15]
//   -> softmax over s = 15 local ops + shfl_xor(16,32). Mask additive.
// P^T bounced via 2KB wave-private LDS ([q][s] bf16, 16B-block XOR swizzle)
// to become the B operand of O^T = V^T.P^T; V^T frags read straight from
// the pre-transposed vt workspace (L2-resident, no staging).
// ---------------------------------------------------------------------------
__global__ __launch_bounds__(256) void attn_mfma(
    const unsigned short* __restrict__ qw, const unsigned short* __restrict__ kw,
    const unsigned short* __restrict__ vtw, const float* __restrict__ msk,
    unsigned short* __restrict__ attn)
{
    __shared__ __align__(16) unsigned short P[4][16 * 64];
    const int tid = threadIdx.x;
    const int l = tid & 63, w = tid >> 6;
    const int lr = l & 15, g = l >> 4;
    const int bh = blockIdx.y, b = bh >> 4, h = bh & 15;
    const int q0 = blockIdx.x * 64 + w * 16;

    const unsigned short* qrow = qw + ((size_t)bh * T_ + q0 + lr) * HD_;
    const bf16x8 qf0 = *(const bf16x8*)&qrow[g * 8];        // B-op: col q=lr, k=d
    const bf16x8 qf1 = *(const bf16x8*)&qrow[32 + g * 8];

    const unsigned short* kb  = kw  + (size_t)bh * T_ * HD_;
    const unsigned short* vtb = vtw + (size_t)bh * HD_ * T_;
    const float* mb = msk + b * T_;
    unsigned short* Pw = P[w];

    f32x4 o[4];
    #pragma unroll
    for (int df = 0; df < 4; ++df) o[df] = f32x4{0.f, 0.f, 0.f, 0.f};
    float m_run = -INFINITY, l_run = 0.f;

    for (int s0 = 0; s0 < T_; s0 += 64) {
        f32x4 st[4];
        #pragma unroll
        for (int sf = 0; sf < 4; ++sf) {                    // S^T = K . Q^T
            const unsigned short* kr = &kb[(size_t)(s0 + sf * 16 + lr) * HD_];
            const bf16x8 k0v = *(const bf16x8*)&kr[g * 8];
            const bf16x8 k1v = *(const bf16x8*)&kr[32 + g * 8];
            f32x4 z = f32x4{0.f, 0.f, 0.f, 0.f};
            z      = __builtin_amdgcn_mfma_f32_16x16x32_bf16(k0v, qf0, z, 0, 0, 0);
            st[sf] = __builtin_amdgcn_mfma_f32_16x16x32_bf16(k1v, qf1, z, 0, 0, 0);
        }
        float pmax = -INFINITY;
        #pragma unroll
        for (int sf = 0; sf < 4; ++sf) {                    // + mask, tile max
            const float4 mv = *(const float4*)&mb[s0 + sf * 16 + g * 4];
            st[sf][0] += mv.x; st[sf][1] += mv.y; st[sf][2] += mv.z; st[sf][3] += mv.w;
            pmax = fmaxf(pmax, fmaxf(fmaxf(st[sf][0], st[sf][1]),
                                     fmaxf(st[sf][2], st[sf][3])));
        }
        pmax = fmaxf(pmax, __shfl_xor(pmax, 16));
        pmax = fmaxf(pmax, __shfl_xor(pmax, 32));
        const float mnew = fmaxf(m_run, pmax);
        const float fac  = __expf(m_run - mnew);            // exp(-inf)=0 first tile
        float rsum = 0.f;
        unsigned int pk[8];
        #pragma unroll
        for (int sf = 0; sf < 4; ++sf) {                    // P = exp(S-m), pack bf16
            const float e0 = __expf(st[sf][0] - mnew), e1 = __expf(st[sf][1] - mnew);
            const float e2 = __expf(st[sf][2] - mnew), e3 = __expf(st[sf][3] - mnew);
            rsum += (e0 + e1) + (e2 + e3);
            pk[sf * 2 + 0] = (unsigned int)f2bf(e0) | ((unsigned int)f2bf(e1) << 16);
            pk[sf * 2 + 1] = (unsigned int)f2bf(e2) | ((unsigned int)f2bf(e3) << 16);
        }
        rsum += __shfl_xor(rsum, 16);
        rsum += __shfl_xor(rsum, 32);
        m_run = mnew;
        l_run = l_run * fac + rsum;
        #pragma unroll
        for (int df = 0; df < 4; ++df) {
            o[df][0] *= fac; o[df][1] *= fac; o[df][2] *= fac; o[df][3] *= fac;
        }
        // P^T -> wave-private LDS as [q=lr][s], 16B-block XOR (blk ^= q&7).
        // Same-wave ds ordering makes write->read safe without barriers.
        #pragma unroll
        for (int sf = 0; sf < 4; ++sf) {
            const int blk = (sf * 2 + (g >> 1)) ^ (lr & 7);
            const int el  = lr * 64 + blk * 8 + (g & 1) * 4;   // s = sf*16+4g+p
            *(unsigned int*)&Pw[el]     = pk[sf * 2 + 0];
            *(unsigned int*)&Pw[el + 2] = pk[sf * 2 + 1];
        }
        #pragma unroll
        for (int ks = 0; ks < 2; ++ks) {                    // O^T += V^T . P^T
            const bf16x8 pf = *(const bf16x8*)&Pw[lr * 64 + (((ks * 4 + g) ^ (lr & 7)) * 8)];
            #pragma unroll
            for (int df = 0; df < 4; ++df) {
                const bf16x8 vf = *(const bf16x8*)
                    &vtb[(size_t)(df * 16 + lr) * T_ + s0 + ks * 32 + g * 8];
                o[df] = __builtin_amdgcn_mfma_f32_16x16x32_bf16(vf, pf, o[df], 0, 0, 0);
            }
        }
    }
    const float inv = 1.f / l_run;
    const int t = q0 + lr;                                  // O^T: col q=lr, row d
    #pragma unroll
    for (int df = 0; df < 4; ++df) {                        // d = df*16 + 4g + p
        ushort4 ov;
        ov.x = f2bf(o[df][0] * inv); ov.y = f2bf(o[df][1] * inv);
        ov.z = f2bf(o[df][2] * inv); ov.w = f2bf(o[df][3] * inv);
        *(ushort4*)&attn[((size_t)t * B_ + b) * E_ + h * HD_ + df * 16 + g * 4] = ov;
    }
}

// ---------------------------------------------------------------------------
extern "C" void kernel_launch(void* const* d_in, const int* in_sizes, int n_in,
                              void* d_out, int out_size, void* d_ws, size_t ws_size,
                              hipStream_t stream)
{
    const float* x     = (const float*)d_in[0];
    const float* w_in  = (const float*)d_in[1];
    const float* b_in  = (const float*)d_in[2];
    const float* w_out = (const float*)d_in[3];
    const float* b_out = (const float*)d_in[4];
    const int*   mask  = (const int*)d_in[5];

    const size_t NX = (size_t)M_ * KD_;        // 4194304
    unsigned short* xb   = (unsigned short*)d_ws;   // also reused as attn buffer
    unsigned short* wib  = xb  + NX;
    unsigned short* wob  = wib + (size_t)N3_ * KD_;
    unsigned short* qb   = wob + (size_t)E_ * KD_;
    unsigned short* kbuf = qb   + NX;
    unsigned short* vbuf = kbuf + NX;
    unsigned short* vtb  = vbuf + NX;
    float*          mskf = (float*)(vtb + NX);
    unsigned short* attnb = xb;                // x dead after gemm<0>

    cvt_bf16<<<(int)(NX / 4 / 256),            256, 0, stream>>>(x,     xb,  (int)(NX / 4));
    cvt_bf16<<<(int)((size_t)N3_*KD_/4/256),   256, 0, stream>>>(w_in,  wib, (int)((size_t)N3_*KD_/4));
    cvt_bf16<<<(int)((size_t)E_*KD_/4/256),    256, 0, stream>>>(w_out, wob, (int)((size_t)E_*KD_/4));
    build_msk<<<(T_*B_ + 255)/256,             256, 0, stream>>>(mask, mskf);

    gemm_mfma<0><<<dim3(N3_/128, M_/128), 256, 0, stream>>>(xb, wib, b_in, qb, kbuf, vbuf, nullptr);
    transpose64 <<<dim3(T_/64, B_*H_),    256, 0, stream>>>(vbuf, vtb);
    attn_mfma   <<<dim3(T_/64, B_*H_),    256, 0, stream>>>(qb, kbuf, vtb, mskf, attnb);
    gemm_mfma<1><<<dim3(E_/128, M_/128),  256, 0, stream>>>(attnb, wob, b_out,
                                                            nullptr, nullptr, nullptr, (float*)d_out);
}

// Round 4
// 240.185 us; speedup vs baseline: 1.6656x; 1.6656x over previous
//
#include <hip/hip_runtime.h>
#include <math.h>

#define T_    2048
#define B_    2
#define E_    1024
#define H_    16
#define HD_   64
#define KD_   1024
#define N3_   3072
#define M_    4096
#define NEGI  -1e24f

typedef __attribute__((ext_vector_type(8))) short          bf16x8;
typedef __attribute__((ext_vector_type(4))) float          f32x4;
typedef __attribute__((ext_vector_type(8))) unsigned short u16x8;

__device__ __forceinline__ unsigned short f2bf(float x) {   // RNE fp32->bf16
    unsigned int u = __float_as_uint(x);
    return (unsigned short)((u + 0x7fffu + ((u >> 16) & 1u)) >> 16);
}

// async global(16B/lane) -> LDS. LDS dest is wave-uniform base + lane*16 (m104);
// source is per-lane (pre-swizzled), LDS stays linear (rule #21 correct form).
__device__ __forceinline__ void gload16(const unsigned short* g, unsigned short* s) {
    __builtin_amdgcn_global_load_lds(
        (const __attribute__((address_space(1))) void*)g,
        (__attribute__((address_space(3))) void*)s, 16, 0, 0);
}

// ---------------------------------------------------------------------------
__global__ __launch_bounds__(256) void cvt_bf16(const float* __restrict__ s,
                                                unsigned short* __restrict__ d, int n4) {
    int i = blockIdx.x * 256 + threadIdx.x;
    if (i >= n4) return;
    float4 v = ((const float4*)s)[i];
    ushort4 o;
    o.x = f2bf(v.x); o.y = f2bf(v.y); o.z = f2bf(v.z); o.w = f2bf(v.w);
    ((ushort4*)d)[i] = o;
}

__global__ __launch_bounds__(256) void build_msk(const int* __restrict__ m,
                                                 float* __restrict__ o) {
    int i = blockIdx.x * 256 + threadIdx.x;          // i = t*B + b
    if (i >= T_ * B_) return;
    o[(i & 1) * T_ + (i >> 1)] = m[i] ? NEGI : 0.f;  // msk[b][t]
}

// ---------------------------------------------------------------------------
// bf16 MFMA GEMM, m97 2-barrier structure with global_load_lds width=16.
// 128x128 tile, BK=64, 4 waves x (64x64 = 4x4 frags of 16x16x32).
// LDS layout: slot f (row=f>>3, blk=f&7) holds global 16B chunk
// [row][blk ^ (row&7)] -> read addr c-block: blk = c ^ (row&7). Conflict-free.
// ---------------------------------------------------------------------------
template <int EPI>
__global__ __launch_bounds__(256) void gemm_mfma(
    const unsigned short* __restrict__ A, const unsigned short* __restrict__ W,
    const float* __restrict__ bias,
    unsigned short* __restrict__ q_o, unsigned short* __restrict__ k_o,
    unsigned short* __restrict__ v_o, float* __restrict__ f_o)
{
    __shared__ __align__(16) unsigned short Ab[128 * 64];
    __shared__ __align__(16) unsigned short Bb[128 * 64];
    const int tid = threadIdx.x;
    const int l = tid & 63, w = tid >> 6;
    const int lr = l & 15, g = l >> 4;
    const int m0 = blockIdx.y * 128, n0 = blockIdx.x * 128;
    const int wr = (w >> 1) * 64, wc = (w & 1) * 64;

    f32x4 acc[4][4];
    #pragma unroll
    for (int i = 0; i < 4; ++i)
        #pragma unroll
        for (int j = 0; j < 4; ++j) acc[i][j] = f32x4{0.f, 0.f, 0.f, 0.f};

    for (int k0 = 0; k0 < KD_; k0 += 64) {
        __syncthreads();                               // prior frag reads done
        #pragma unroll
        for (int i = 0; i < 4; ++i) {
            const int fb  = (i * 4 + w) * 64;          // wave-uniform slot base
            const int row = (fb + l) >> 3;
            const int col = ((l & 7) ^ (row & 7)) * 8; // pre-swizzled source
            gload16(&A[(size_t)(m0 + row) * KD_ + k0 + col], &Ab[fb * 8]);
            gload16(&W[(size_t)(n0 + row) * KD_ + k0 + col], &Bb[fb * 8]);
        }
        __syncthreads();                               // vmcnt(0) drain -> ready
        #pragma unroll
        for (int ks = 0; ks < 2; ++ks) {
            bf16x8 af[4], bf[4];
            #pragma unroll
            for (int mi = 0; mi < 4; ++mi) {
                const int row = wr + mi * 16 + lr;
                af[mi] = *(const bf16x8*)&Ab[row * 64 + (((ks * 4 + g) ^ (row & 7)) * 8)];
            }
            #pragma unroll
            for (int ni = 0; ni < 4; ++ni) {
                const int row = wc + ni * 16 + lr;
                bf[ni] = *(const bf16x8*)&Bb[row * 64 + (((ks * 4 + g) ^ (row & 7)) * 8)];
            }
            #pragma unroll
            for (int mi = 0; mi < 4; ++mi)
                #pragma unroll
                for (int ni = 0; ni < 4; ++ni)
                    acc[mi][ni] = __builtin_amdgcn_mfma_f32_16x16x32_bf16(
                        af[mi], bf[ni], acc[mi][ni], 0, 0, 0);
        }
    }

    // C/D layout: col = lane&15, row = (lane>>4)*4 + reg   [m89-verified]
    if (EPI == 0) {
        const int sec = n0 >> 10;                      // 0=q 1=k 2=v
        unsigned short* dst = (sec == 0) ? q_o : (sec == 1) ? k_o : v_o;
        const float sc = (sec == 0) ? 0.125f : 1.f;    // hd^-0.5
        #pragma unroll
        for (int ni = 0; ni < 4; ++ni) {
            const int fcol = n0 + wc + ni * 16 + lr;
            const int h = (fcol >> 6) & 15, d = fcol & 63;
            const float bv = bias[fcol];
            #pragma unroll
            for (int mi = 0; mi < 4; ++mi)
                #pragma unroll
                for (int p = 0; p < 4; ++p) {
                    const int m = m0 + wr + mi * 16 + g * 4 + p;
                    const int t = m >> 1, b = m & 1;   // row m = t*B + b
                    dst[((size_t)(b * H_ + h) * T_ + t) * HD_ + d] =
                        f2bf((acc[mi][ni][p] + bv) * sc);
                }
        }
    } else {
        #pragma unroll
        for (int ni = 0; ni < 4; ++ni) {
            const int fcol = n0 + wc + ni * 16 + lr;
            const float bv = bias[fcol];
            #pragma unroll
            for (int mi = 0; mi < 4; ++mi)
                #pragma unroll
                for (int p = 0; p < 4; ++p) {
                    const int m = m0 + wr + mi * 16 + g * 4 + p;
                    f_o[(size_t)m * E_ + fcol] = acc[mi][ni][p] + bv;
                }
        }
    }
}

// ---------------------------------------------------------------------------
// V [bh][t][d] -> Vt [bh][d][t]  (64x64 tiles through LDS)
// ---------------------------------------------------------------------------
__global__ __launch_bounds__(256) void transpose64(const unsigned short* __restrict__ v,
                                                   unsigned short* __restrict__ vt)
{
    __shared__ __align__(16) unsigned short tile[64][72];
    const int bh = blockIdx.y, t0 = blockIdx.x * 64;
    const int tid = threadIdx.x;
    const int r = tid >> 2, c0 = (tid & 3) * 16;
    const unsigned short* src = v + ((size_t)bh * T_ + t0 + r) * HD_ + c0;
    *(u16x8*)&tile[r][c0]     = *(const u16x8*)&src[0];
    *(u16x8*)&tile[r][c0 + 8] = *(const u16x8*)&src[8];
    __syncthreads();
    u16x8 a, b;
    #pragma unroll
    for (int j = 0; j < 8; ++j) a[j] = tile[c0 + j][r];       // r is d here
    #pragma unroll
    for (int j = 0; j < 8; ++j) b[j] = tile[c0 + 8 + j][r];
    unsigned short* dq = vt + ((size_t)bh * HD_ + r) * T_ + t0 + c0;
    *(u16x8*)&dq[0] = a;
    *(u16x8*)&dq[8] = b;
}

// stage one 64x64 bf16 tile (row stride ld) into swizzled LDS via gload_lds.
// 512 slots = 2 chunks x 4 waves x 64 lanes.
__device__ __forceinline__ void stage64(const unsigned short* src, int ld,
                                        unsigned short* buf, int w, int l) {
    #pragma unroll
    for (int c = 0; c < 2; ++c) {
        const int fb  = (c * 4 + w) * 64;
        const int row = (fb + l) >> 3;
        const int col = ((l & 7) ^ (row & 7)) * 8;
        gload16(src + (size_t)row * ld + col, buf + fb * 8);
    }
}

// ---------------------------------------------------------------------------
// Flash attention v2: block = 4 waves, QBLK=128 (32 q/wave, 2 col-frags),
// KVBLK=64. K[s][d] and Vt[d][s] staged cooperatively in double-buffered
// swizzled LDS; async prefetch of tile t+1 issued at top of tile t (overlaps
// full compute phase); ONE barrier per tile. Swapped QK^T (S^T = K.Q^T) keeps
// softmax s-axis in-lane: reduce = 15 VALU + 2 shfl_xor. P bounced via
// wave-private swizzled LDS (b64 writes, bandwidth-floor banking).
// ---------------------------------------------------------------------------
__global__ __launch_bounds__(256, 3) void attn_mfma(
    const unsigned short* __restrict__ qw, const unsigned short* __restrict__ kw,
    const unsigned short* __restrict__ vtw, const float* __restrict__ msk,
    unsigned short* __restrict__ attn)
{
    __shared__ __align__(16) unsigned short Kb[2][64 * 64];   // 8 KB each
    __shared__ __align__(16) unsigned short Vb[2][64 * 64];
    __shared__ __align__(16) unsigned short Pb[4][32 * 64];   // 4 KB/wave

    const int tid = threadIdx.x;
    const int l = tid & 63, w = tid >> 6;
    const int lr = l & 15, g = l >> 4;
    const int bh = blockIdx.y, b = bh >> 4, h = bh & 15;
    const int q0 = blockIdx.x * 128 + w * 32;

    const unsigned short* kb  = kw  + (size_t)bh * T_ * HD_;
    const unsigned short* vtb = vtw + (size_t)bh * HD_ * T_;
    const float* mb = msk + b * T_;
    unsigned short* Pw = Pb[w];

    bf16x8 qf[2][2];                       // B-op: col q = lr, k = d
    #pragma unroll
    for (int qc = 0; qc < 2; ++qc) {
        const unsigned short* qrow = qw + ((size_t)bh * T_ + q0 + qc * 16 + lr) * HD_;
        qf[qc][0] = *(const bf16x8*)&qrow[g * 8];
        qf[qc][1] = *(const bf16x8*)&qrow[32 + g * 8];
    }

    f32x4 o[2][4];
    #pragma unroll
    for (int qc = 0; qc < 2; ++qc)
        #pragma unroll
        for (int df = 0; df < 4; ++df) o[qc][df] = f32x4{0.f, 0.f, 0.f, 0.f};
    float m_run[2] = {-INFINITY, -INFINITY}, l_run[2] = {0.f, 0.f};

    stage64(kb, HD_, Kb[0], w, l);               // prologue: tile 0 in flight
    stage64(vtb, T_, Vb[0], w, l);
    int cur = 0;

    for (int s0 = 0; s0 < T_; s0 += 64) {
        __syncthreads();     // drains vmcnt -> buf[cur] ready; buf[cur^1] free
        if (s0 + 64 < T_) {                      // async prefetch next tile
            stage64(kb + (size_t)(s0 + 64) * HD_, HD_, Kb[cur ^ 1], w, l);
            stage64(vtb + (s0 + 64),          T_, Vb[cur ^ 1], w, l);
        }
        const unsigned short* Kc = Kb[cur];
        const unsigned short* Vc = Vb[cur];

        f32x4 st[4][2];                          // S^T = K . Q^T
        #pragma unroll
        for (int sf = 0; sf < 4; ++sf) {
            const int row = sf * 16 + lr;
            const bf16x8 k0v = *(const bf16x8*)&Kc[row * 64 + ((g       ^ (row & 7)) * 8)];
            const bf16x8 k1v = *(const bf16x8*)&Kc[row * 64 + (((4 + g) ^ (row & 7)) * 8)];
            #pragma unroll
            for (int qc = 0; qc < 2; ++qc) {
                f32x4 z = f32x4{0.f, 0.f, 0.f, 0.f};
                z           = __builtin_amdgcn_mfma_f32_16x16x32_bf16(k0v, qf[qc][0], z, 0, 0, 0);
                st[sf][qc]  = __builtin_amdgcn_mfma_f32_16x16x32_bf16(k1v, qf[qc][1], z, 0, 0, 0);
            }
        }
        float4 mv[4];
        #pragma unroll
        for (int sf = 0; sf < 4; ++sf) mv[sf] = *(const float4*)&mb[s0 + sf * 16 + g * 4];

        #pragma unroll
        for (int qc = 0; qc < 2; ++qc) {         // online softmax (s in-lane)
            float pmax = -INFINITY;
            #pragma unroll
            for (int sf = 0; sf < 4; ++sf) {
                st[sf][qc][0] += mv[sf].x; st[sf][qc][1] += mv[sf].y;
                st[sf][qc][2] += mv[sf].z; st[sf][qc][3] += mv[sf].w;
                pmax = fmaxf(pmax, fmaxf(fmaxf(st[sf][qc][0], st[sf][qc][1]),
                                         fmaxf(st[sf][qc][2], st[sf][qc][3])));
            }
            pmax = fmaxf(pmax, __shfl_xor(pmax, 16));
            pmax = fmaxf(pmax, __shfl_xor(pmax, 32));
            const float mnew = fmaxf(m_run[qc], pmax);
            const float fac  = __expf(m_run[qc] - mnew);   // exp(-inf)=0 first tile
            float rsum = 0.f;
            unsigned int pk[8];
            #pragma unroll
            for (int sf = 0; sf < 4; ++sf) {
                const float e0 = __expf(st[sf][qc][0] - mnew), e1 = __expf(st[sf][qc][1] - mnew);
                const float e2 = __expf(st[sf][qc][2] - mnew), e3 = __expf(st[sf][qc][3] - mnew);
                rsum += (e0 + e1) + (e2 + e3);
                pk[sf * 2 + 0] = (unsigned int)f2bf(e0) | ((unsigned int)f2bf(e1) << 16);
                pk[sf * 2 + 1] = (unsigned int)f2bf(e2) | ((unsigned int)f2bf(e3) << 16);
            }
            rsum += __shfl_xor(rsum, 16);
            rsum += __shfl_xor(rsum, 32);
            m_run[qc] = mnew;
            l_run[qc] = l_run[qc] * fac + rsum;
            #pragma unroll
            for (int df = 0; df < 4; ++df) {
                o[qc][df][0] *= fac; o[qc][df][1] *= fac;
                o[qc][df][2] *= fac; o[qc][df][3] *= fac;
            }
            const int prow = qc * 16 + lr;       // P^T -> wave-private LDS [q][s]
            #pragma unroll
            for (int sf = 0; sf < 4; ++sf) {
                const int blkS = (sf * 2 + (g >> 1)) ^ (prow & 7);
                uint2 val; val.x = pk[sf * 2]; val.y = pk[sf * 2 + 1];
                *(uint2*)&Pw[prow * 64 + blkS * 8 + (g & 1) * 4] = val;
            }
        }

        #pragma unroll
        for (int ks = 0; ks < 2; ++ks) {         // O^T += V^T . P^T
            bf16x8 pf[2];
            #pragma unroll
            for (int qc = 0; qc < 2; ++qc) {
                const int prow = qc * 16 + lr;
                pf[qc] = *(const bf16x8*)&Pw[prow * 64 + (((ks * 4 + g) ^ (prow & 7)) * 8)];
            }
            #pragma unroll
            for (int df = 0; df < 4; ++df) {
                const int vrow = df * 16 + lr;
                const bf16x8 vf = *(const bf16x8*)&Vc[vrow * 64 + (((ks * 4 + g) ^ (vrow & 7)) * 8)];
                #pragma unroll
                for (int qc = 0; qc < 2; ++qc)
                    o[qc][df] = __builtin_amdgcn_mfma_f32_16x16x32_bf16(vf, pf[qc], o[qc][df], 0, 0, 0);
            }
        }
        cur ^= 1;
    }

    #pragma unroll
    for (int qc = 0; qc < 2; ++qc) {             // O^T: col q = lr, row d
        const float inv = 1.f / l_run[qc];
        const int t = q0 + qc * 16 + lr;
        #pragma unroll
        for (int df = 0; df < 4; ++df) {         // d = df*16 + g*4 + p
            ushort4 ov;
            ov.x = f2bf(o[qc][df][0] * inv); ov.y = f2bf(o[qc][df][1] * inv);
            ov.z = f2bf(o[qc][df][2] * inv); ov.w = f2bf(o[qc][df][3] * inv);
            *(ushort4*)&attn[((size_t)t * B_ + b) * E_ + h * HD_ + df * 16 + g * 4] = ov;
        }
    }
}

// ---------------------------------------------------------------------------
extern "C" void kernel_launch(void* const* d_in, const int* in_sizes, int n_in,
                              void* d_out, int out_size, void* d_ws, size_t ws_size,
                              hipStream_t stream)
{
    const float* x     = (const float*)d_in[0];
    const float* w_in  = (const float*)d_in[1];
    const float* b_in  = (const float*)d_in[2];
    const float* w_out = (const float*)d_in[3];
    const float* b_out = (const float*)d_in[4];
    const int*   mask  = (const int*)d_in[5];

    const size_t NX = (size_t)M_ * KD_;        // 4194304
    unsigned short* xb   = (unsigned short*)d_ws;   // reused as attn buffer
    unsigned short* wib  = xb  + NX;
    unsigned short* wob  = wib + (size_t)N3_ * KD_;
    unsigned short* qb   = wob + (size_t)E_ * KD_;
    unsigned short* kbuf = qb   + NX;
    unsigned short* vbuf = kbuf + NX;
    unsigned short* vtb  = vbuf + NX;
    float*          mskf = (float*)(vtb + NX);
    unsigned short* attnb = xb;                // x dead after gemm<0>

    cvt_bf16<<<(int)(NX / 4 / 256),            256, 0, stream>>>(x,     xb,  (int)(NX / 4));
    cvt_bf16<<<(int)((size_t)N3_*KD_/4/256),   256, 0, stream>>>(w_in,  wib, (int)((size_t)N3_*KD_/4));
    cvt_bf16<<<(int)((size_t)E_*KD_/4/256),    256, 0, stream>>>(w_out, wob, (int)((size_t)E_*KD_/4));
    build_msk<<<(T_*B_ + 255)/256,             256, 0, stream>>>(mask, mskf);

    gemm_mfma<0><<<dim3(N3_/128, M_/128), 256, 0, stream>>>(xb, wib, b_in, qb, kbuf, vbuf, nullptr);
    transpose64 <<<dim3(T_/64, B_*H_),    256, 0, stream>>>(vbuf, vtb);
    attn_mfma   <<<dim3(T_/128, B_*H_),   256, 0, stream>>>(qb, kbuf, vtb, mskf, attnb);
    gemm_mfma<1><<<dim3(E_/128, M_/128),  256, 0, stream>>>(attnb, wob, b_out,
                                                            nullptr, nullptr, nullptr, (float*)d_out);
}

// Round 5
// 230.817 us; speedup vs baseline: 1.7332x; 1.0406x over previous
//
#include <hip/hip_runtime.h>
#include <math.h>

#define T_    2048
#define B_    2
#define E_    1024
#define H_    16
#define HD_   64
#define KD_   1024
#define N3_   3072
#define M_    4096
#define NEGI  -1e24f

typedef __attribute__((ext_vector_type(8))) short          bf16x8;
typedef __attribute__((ext_vector_type(4))) float          f32x4;
typedef __attribute__((ext_vector_type(8))) unsigned short u16x8;

__device__ __forceinline__ unsigned short f2bf(float x) {   // RNE fp32->bf16
    unsigned int u = __float_as_uint(x);
    return (unsigned short)((u + 0x7fffu + ((u >> 16) & 1u)) >> 16);
}

// pack two f32 -> one dword of 2 bf16 (lo = a, hi = b), HW RNE (T12 recipe)
__device__ __forceinline__ unsigned int cvtpk_bf16(float a, float b) {
    unsigned int r;
    asm("v_cvt_pk_bf16_f32 %0, %1, %2" : "=v"(r) : "v"(a), "v"(b));
    return r;
}

// async global(16B/lane) -> LDS. LDS dest is wave-uniform base + lane*16 (m104);
// source is per-lane (pre-swizzled), LDS stays linear (rule #21 correct form).
__device__ __forceinline__ void gload16(const unsigned short* g, unsigned short* s) {
    __builtin_amdgcn_global_load_lds(
        (const __attribute__((address_space(1))) void*)g,
        (__attribute__((address_space(3))) void*)s, 16, 0, 0);
}

// ---------------------------------------------------------------------------
// fused fp32->bf16 for x, w_in, w_out (dsts contiguous in ws at xb)
#define XN4  ((size_t)M_ * KD_ / 4)
#define WIN4 ((size_t)N3_ * KD_ / 4)
#define WON4 ((size_t)E_ * KD_ / 4)
__global__ __launch_bounds__(256) void cvt_all(const float* __restrict__ x,
                                               const float* __restrict__ wi,
                                               const float* __restrict__ wo,
                                               unsigned short* __restrict__ dst) {
    const size_t i = (size_t)blockIdx.x * 256 + threadIdx.x;
    const float* s; size_t off;
    if (i < XN4)             { s = x;  off = i; }
    else if (i < XN4 + WIN4) { s = wi; off = i - XN4; }
    else                     { s = wo; off = i - XN4 - WIN4; }
    float4 v = ((const float4*)s)[off];
    ushort4 o;
    o.x = f2bf(v.x); o.y = f2bf(v.y); o.z = f2bf(v.z); o.w = f2bf(v.w);
    ((ushort4*)dst)[i] = o;
}

__global__ __launch_bounds__(256) void build_msk(const int* __restrict__ m,
                                                 float* __restrict__ o) {
    int i = blockIdx.x * 256 + threadIdx.x;          // i = t*B + b
    if (i >= T_ * B_) return;
    o[(i & 1) * T_ + (i >> 1)] = m[i] ? NEGI : 0.f;  // msk[b][t]
}

// ---------------------------------------------------------------------------
// bf16 MFMA GEMM, m97 2-barrier structure with global_load_lds width=16.
// 128x128 tile, BK=64, 4 waves x (64x64 = 4x4 frags of 16x16x32).
// LDS slot f (row=f>>3, blk=f&7) holds global 16B chunk [row][blk^(row&7)].
// ---------------------------------------------------------------------------
template <int EPI>
__global__ __launch_bounds__(256) void gemm_mfma(
    const unsigned short* __restrict__ A, const unsigned short* __restrict__ W,
    const float* __restrict__ bias,
    unsigned short* __restrict__ q_o, unsigned short* __restrict__ k_o,
    unsigned short* __restrict__ v_o, float* __restrict__ f_o)
{
    __shared__ __align__(16) unsigned short Ab[128 * 64];
    __shared__ __align__(16) unsigned short Bb[128 * 64];
    const int tid = threadIdx.x;
    const int l = tid & 63, w = tid >> 6;
    const int lr = l & 15, g = l >> 4;
    const int m0 = blockIdx.y * 128, n0 = blockIdx.x * 128;
    const int wr = (w >> 1) * 64, wc = (w & 1) * 64;

    f32x4 acc[4][4];
    #pragma unroll
    for (int i = 0; i < 4; ++i)
        #pragma unroll
        for (int j = 0; j < 4; ++j) acc[i][j] = f32x4{0.f, 0.f, 0.f, 0.f};

    for (int k0 = 0; k0 < KD_; k0 += 64) {
        __syncthreads();                               // prior frag reads done
        #pragma unroll
        for (int i = 0; i < 4; ++i) {
            const int fb  = (i * 4 + w) * 64;          // wave-uniform slot base
            const int row = (fb + l) >> 3;
            const int col = ((l & 7) ^ (row & 7)) * 8; // pre-swizzled source
            gload16(&A[(size_t)(m0 + row) * KD_ + k0 + col], &Ab[fb * 8]);
            gload16(&W[(size_t)(n0 + row) * KD_ + k0 + col], &Bb[fb * 8]);
        }
        __syncthreads();                               // vmcnt(0) drain -> ready
        #pragma unroll
        for (int ks = 0; ks < 2; ++ks) {
            bf16x8 af[4], bf[4];
            #pragma unroll
            for (int mi = 0; mi < 4; ++mi) {
                const int row = wr + mi * 16 + lr;
                af[mi] = *(const bf16x8*)&Ab[row * 64 + (((ks * 4 + g) ^ (row & 7)) * 8)];
            }
            #pragma unroll
            for (int ni = 0; ni < 4; ++ni) {
                const int row = wc + ni * 16 + lr;
                bf[ni] = *(const bf16x8*)&Bb[row * 64 + (((ks * 4 + g) ^ (row & 7)) * 8)];
            }
            #pragma unroll
            for (int mi = 0; mi < 4; ++mi)
                #pragma unroll
                for (int ni = 0; ni < 4; ++ni)
                    acc[mi][ni] = __builtin_amdgcn_mfma_f32_16x16x32_bf16(
                        af[mi], bf[ni], acc[mi][ni], 0, 0, 0);
        }
    }

    // C/D layout: col = lane&15, row = (lane>>4)*4 + reg   [m89-verified]
    if (EPI == 0) {
        const int sec = n0 >> 10;                      // 0=q 1=k 2=v
        unsigned short* dst = (sec == 0) ? q_o : (sec == 1) ? k_o : v_o;
        const float sc = (sec == 0) ? 0.125f : 1.f;    // hd^-0.5
        #pragma unroll
        for (int ni = 0; ni < 4; ++ni) {
            const int fcol = n0 + wc + ni * 16 + lr;
            const int h = (fcol >> 6) & 15, d = fcol & 63;
            const float bv = bias[fcol];
            #pragma unroll
            for (int mi = 0; mi < 4; ++mi)
                #pragma unroll
                for (int p = 0; p < 4; ++p) {
                    const int m = m0 + wr + mi * 16 + g * 4 + p;
                    const int t = m >> 1, b = m & 1;   // row m = t*B + b
                    dst[((size_t)(b * H_ + h) * T_ + t) * HD_ + d] =
                        f2bf((acc[mi][ni][p] + bv) * sc);
                }
        }
    } else {
        #pragma unroll
        for (int ni = 0; ni < 4; ++ni) {
            const int fcol = n0 + wc + ni * 16 + lr;
            const float bv = bias[fcol];
            #pragma unroll
            for (int mi = 0; mi < 4; ++mi)
                #pragma unroll
                for (int p = 0; p < 4; ++p) {
                    const int m = m0 + wr + mi * 16 + g * 4 + p;
                    f_o[(size_t)m * E_ + fcol] = acc[mi][ni][p] + bv;
                }
        }
    }
}

// ---------------------------------------------------------------------------
// V [bh][t][d] -> Vt [bh][d][t]  (64x64 tiles through LDS)
// ---------------------------------------------------------------------------
__global__ __launch_bounds__(256) void transpose64(const unsigned short* __restrict__ v,
                                                   unsigned short* __restrict__ vt)
{
    __shared__ __align__(16) unsigned short tile[64][72];
    const int bh = blockIdx.y, t0 = blockIdx.x * 64;
    const int tid = threadIdx.x;
    const int r = tid >> 2, c0 = (tid & 3) * 16;
    const unsigned short* src = v + ((size_t)bh * T_ + t0 + r) * HD_ + c0;
    *(u16x8*)&tile[r][c0]     = *(const u16x8*)&src[0];
    *(u16x8*)&tile[r][c0 + 8] = *(const u16x8*)&src[8];
    __syncthreads();
    u16x8 a, b;
    #pragma unroll
    for (int j = 0; j < 8; ++j) a[j] = tile[c0 + j][r];       // r is d here
    #pragma unroll
    for (int j = 0; j < 8; ++j) b[j] = tile[c0 + 8 + j][r];
    unsigned short* dq = vt + ((size_t)bh * HD_ + r) * T_ + t0 + c0;
    *(u16x8*)&dq[0] = a;
    *(u16x8*)&dq[8] = b;
}

// stage one 64x64 bf16 tile (row stride ld) into swizzled LDS, 8 waves:
// wave w stages slots w*64..w*64+63, one gload16 per lane.
__device__ __forceinline__ void stage8(const unsigned short* src, int ld,
                                       unsigned short* buf, int w, int l) {
    const int fb  = w * 64;
    const int row = (fb + l) >> 3;
    const int col = ((l & 7) ^ (row & 7)) * 8;
    gload16(src + (size_t)row * ld + col, buf + fb * 8);
}

// ---------------------------------------------------------------------------
// Flash attention v3: 8 waves (512 thr), QBLK=256 (32 q/wave, qc=2), KVBLK=64.
// 21.8 MAC per LDS byte (above the 16 MAC/B LDS-balance point). K[s][d] and
// Vt[d][s] double-buffered swizzled LDS, async gload_lds prefetch, ONE barrier
// per tile. Swapped QK^T keeps softmax s-axis in-lane. P packed via
// v_cvt_pk_bf16_f32; defer-max (THR=8) skips o/l rescale on most tiles.
// ---------------------------------------------------------------------------
__global__ __launch_bounds__(512, 2) void attn_mfma(
    const unsigned short* __restrict__ qw, const unsigned short* __restrict__ kw,
    const unsigned short* __restrict__ vtw, const float* __restrict__ msk,
    unsigned short* __restrict__ attn)
{
    __shared__ __align__(16) unsigned short Kb[2][64 * 64];   // 8 KB each
    __shared__ __align__(16) unsigned short Vb[2][64 * 64];
    __shared__ __align__(16) unsigned short Pb[8][32 * 64];   // 4 KB/wave

    const int tid = threadIdx.x;
    const int l = tid & 63, w = tid >> 6;
    const int lr = l & 15, g = l >> 4;
    const int bh = blockIdx.y, b = bh >> 4, h = bh & 15;
    const int q0 = blockIdx.x * 256 + w * 32;

    const unsigned short* kb  = kw  + (size_t)bh * T_ * HD_;
    const unsigned short* vtb = vtw + (size_t)bh * HD_ * T_;
    const float* mb = msk + b * T_;
    unsigned short* Pw = Pb[w];

    bf16x8 qf[2][2];                       // B-op: col q = lr, k = d
    #pragma unroll
    for (int qc = 0; qc < 2; ++qc) {
        const unsigned short* qrow = qw + ((size_t)bh * T_ + q0 + qc * 16 + lr) * HD_;
        qf[qc][0] = *(const bf16x8*)&qrow[g * 8];
        qf[qc][1] = *(const bf16x8*)&qrow[32 + g * 8];
    }

    f32x4 o[2][4];
    #pragma unroll
    for (int qc = 0; qc < 2; ++qc)
        #pragma unroll
        for (int df = 0; df < 4; ++df) o[qc][df] = f32x4{0.f, 0.f, 0.f, 0.f};
    float m_run[2] = {-INFINITY, -INFINITY}, l_run[2] = {0.f, 0.f};

    stage8(kb, HD_, Kb[0], w, l);                // prologue: tile 0 in flight
    stage8(vtb, T_, Vb[0], w, l);
    int cur = 0;

    for (int s0 = 0; s0 < T_; s0 += 64) {
        __syncthreads();     // drains vmcnt -> buf[cur] ready; buf[cur^1] free
        if (s0 + 64 < T_) {                      // async prefetch next tile
            stage8(kb + (size_t)(s0 + 64) * HD_, HD_, Kb[cur ^ 1], w, l);
            stage8(vtb + (s0 + 64),          T_, Vb[cur ^ 1], w, l);
        }
        const unsigned short* Kc = Kb[cur];
        const unsigned short* Vc = Vb[cur];

        f32x4 st[4][2];                          // S^T = K . Q^T
        #pragma unroll
        for (int sf = 0; sf < 4; ++sf) {
            const int row = sf * 16 + lr;
            const bf16x8 k0v = *(const bf16x8*)&Kc[row * 64 + ((g       ^ (row & 7)) * 8)];
            const bf16x8 k1v = *(const bf16x8*)&Kc[row * 64 + (((4 + g) ^ (row & 7)) * 8)];
            #pragma unroll
            for (int qc = 0; qc < 2; ++qc) {
                f32x4 z = f32x4{0.f, 0.f, 0.f, 0.f};
                z           = __builtin_amdgcn_mfma_f32_16x16x32_bf16(k0v, qf[qc][0], z, 0, 0, 0);
                st[sf][qc]  = __builtin_amdgcn_mfma_f32_16x16x32_bf16(k1v, qf[qc][1], z, 0, 0, 0);
            }
        }
        float4 mv[4];
        #pragma unroll
        for (int sf = 0; sf < 4; ++sf) mv[sf] = *(const float4*)&mb[s0 + sf * 16 + g * 4];

        #pragma unroll
        for (int qc = 0; qc < 2; ++qc) {         // online softmax (s in-lane)
            float pmax = -INFINITY;
            #pragma unroll
            for (int sf = 0; sf < 4; ++sf) {
                st[sf][qc][0] += mv[sf].x; st[sf][qc][1] += mv[sf].y;
                st[sf][qc][2] += mv[sf].z; st[sf][qc][3] += mv[sf].w;
                pmax = fmaxf(pmax, fmaxf(fmaxf(st[sf][qc][0], st[sf][qc][1]),
                                         fmaxf(st[sf][qc][2], st[sf][qc][3])));
            }
            pmax = fmaxf(pmax, __shfl_xor(pmax, 16));
            pmax = fmaxf(pmax, __shfl_xor(pmax, 32));
            // defer-max (T13): only rescale when the stale max is >8 behind.
            if (!__all(pmax - m_run[qc] <= 8.f)) {
                const float mnew = fmaxf(m_run[qc], pmax);
                const float fac  = __expf(m_run[qc] - mnew);  // exp(-inf)=0 tile 0
                l_run[qc] *= fac;
                #pragma unroll
                for (int df = 0; df < 4; ++df) {
                    o[qc][df][0] *= fac; o[qc][df][1] *= fac;
                    o[qc][df][2] *= fac; o[qc][df][3] *= fac;
                }
                m_run[qc] = mnew;
            }
            const float mcur = m_run[qc];
            float rsum = 0.f;
            unsigned int pk[8];
            #pragma unroll
            for (int sf = 0; sf < 4; ++sf) {     // P = exp(S-m) <= e^8, pack bf16
                const float e0 = __expf(st[sf][qc][0] - mcur), e1 = __expf(st[sf][qc][1] - mcur);
                const float e2 = __expf(st[sf][qc][2] - mcur), e3 = __expf(st[sf][qc][3] - mcur);
                rsum += (e0 + e1) + (e2 + e3);
                pk[sf * 2 + 0] = cvtpk_bf16(e0, e1);
                pk[sf * 2 + 1] = cvtpk_bf16(e2, e3);
            }
            rsum += __shfl_xor(rsum, 16);
            rsum += __shfl_xor(rsum, 32);
            l_run[qc] += rsum;
            const int prow = qc * 16 + lr;       // P^T -> wave-private LDS [q][s]
            #pragma unroll
            for (int sf = 0; sf < 4; ++sf) {
                const int blkS = (sf * 2 + (g >> 1)) ^ (prow & 7);
                uint2 val; val.x = pk[sf * 2]; val.y = pk[sf * 2 + 1];
                *(uint2*)&Pw[prow * 64 + blkS * 8 + (g & 1) * 4] = val;
            }
        }

        #pragma unroll
        for (int ks = 0; ks < 2; ++ks) {         // O^T += V^T . P^T
            bf16x8 pf[2];
            #pragma unroll
            for (int qc = 0; qc < 2; ++qc) {
                const int prow = qc * 16 + lr;
                pf[qc] = *(const bf16x8*)&Pw[prow * 64 + (((ks * 4 + g) ^ (prow & 7)) * 8)];
            }
            #pragma unroll
            for (int df = 0; df < 4; ++df) {
                const int vrow = df * 16 + lr;
                const bf16x8 vf = *(const bf16x8*)&Vc[vrow * 64 + (((ks * 4 + g) ^ (vrow & 7)) * 8)];
                #pragma unroll
                for (int qc = 0; qc < 2; ++qc)
                    o[qc][df] = __builtin_amdgcn_mfma_f32_16x16x32_bf16(vf, pf[qc], o[qc][df], 0, 0, 0);
            }
        }
        cur ^= 1;
    }

    #pragma unroll
    for (int qc = 0; qc < 2; ++qc) {             // O^T: col q = lr, row d
        const float inv = 1.f / l_run[qc];
        const int t = q0 + qc * 16 + lr;
        #pragma unroll
        for (int df = 0; df < 4; ++df) {         // d = df*16 + g*4 + p
            ushort4 ov;
            ov.x = f2bf(o[qc][df][0] * inv); ov.y = f2bf(o[qc][df][1] * inv);
            ov.z = f2bf(o[qc][df][2] * inv); ov.w = f2bf(o[qc][df][3] * inv);
            *(ushort4*)&attn[((size_t)t * B_ + b) * E_ + h * HD_ + df * 16 + g * 4] = ov;
        }
    }
}

// ---------------------------------------------------------------------------
extern "C" void kernel_launch(void* const* d_in, const int* in_sizes, int n_in,
                              void* d_out, int out_size, void* d_ws, size_t ws_size,
                              hipStream_t stream)
{
    const float* x     = (const float*)d_in[0];
    const float* w_in  = (const float*)d_in[1];
    const float* b_in  = (const float*)d_in[2];
    const float* w_out = (const float*)d_in[3];
    const float* b_out = (const float*)d_in[4];
    const int*   mask  = (const int*)d_in[5];

    const size_t NX = (size_t)M_ * KD_;        // 4194304
    unsigned short* xb   = (unsigned short*)d_ws;   // reused as attn buffer
    unsigned short* wib  = xb  + NX;
    unsigned short* wob  = wib + (size_t)N3_ * KD_;
    unsigned short* qb   = wob + (size_t)E_ * KD_;
    unsigned short* kbuf = qb   + NX;
    unsigned short* vbuf = kbuf + NX;
    unsigned short* vtb  = vbuf + NX;
    float*          mskf = (float*)(vtb + NX);
    unsigned short* attnb = xb;                // x dead after gemm<0>

    const int cvt_blocks = (int)((XN4 + WIN4 + WON4) / 256);
    cvt_all  <<<cvt_blocks,        256, 0, stream>>>(x, w_in, w_out, xb);
    build_msk<<<(T_*B_ + 255)/256, 256, 0, stream>>>(mask, mskf);

    gemm_mfma<0><<<dim3(N3_/128, M_/128), 256, 0, stream>>>(xb, wib, b_in, qb, kbuf, vbuf, nullptr);
    transpose64 <<<dim3(T_/64, B_*H_),    256, 0, stream>>>(vbuf, vtb);
    attn_mfma   <<<dim3(T_/256, B_*H_),   512, 0, stream>>>(qb, kbuf, vtb, mskf, attnb);
    gemm_mfma<1><<<dim3(E_/128, M_/128),  256, 0, stream>>>(attnb, wob, b_out,
                                                            nullptr, nullptr, nullptr, (float*)d_out);
}